// Round 7
// baseline (1175.771 us; speedup 1.0000x reference)
//
#include <hip/hip_runtime.h>

#define BATCH 64
#define ATOMS 64
#define CIN 3
#define KS 8
#define H 224
#define W 224
#define OH 56
#define OW 56
#define NLAT (BATCH*ATOMS*OH*OW)   // 12,845,056
#define IMGSZ (OH*OW*ATOMS)        // 200,704 elems per image (channel-last)
#define LAM 0.1f
#define ETA 0.1f

typedef __attribute__((ext_vector_type(8)))  __bf16    bf16x8;
typedef __attribute__((ext_vector_type(8)))  _Float16  f16x8;
typedef __attribute__((ext_vector_type(16))) float     floatx16;

union FragU { uint4 u; bf16x8 v; };
union FragH { uint4 u; f16x8 v; };
union HalfBits { _Float16 h; unsigned short s; };

__device__ __forceinline__ float softthr(float u) {
    float p = u - LAM;  p = p > 0.f ? p : 0.f;
    float q = -u - LAM; q = q > 0.f ? q : 0.f;
    return p - q;
}
__device__ __forceinline__ unsigned short f2bf(float f) {   // RNE
    union { float f; unsigned int u; } c; c.f = f;
    unsigned int r = c.u + 0x7fffu + ((c.u >> 16) & 1u);
    return (unsigned short)(r >> 16);
}
__device__ __forceinline__ float bf2f(unsigned short h) {
    union { unsigned int u; float f; } c; c.u = ((unsigned int)h) << 16;
    return c.f;
}
__device__ __forceinline__ unsigned short f2h(float f) {    // fp16 bits, RNE
    HalfBits hb; hb.h = (_Float16)f; return hb.s;
}
__device__ __forceinline__ float h2f(unsigned short s) {
    HalfBits hb; hb.s = s; return (float)hb.h;
}

// DT[((c*8+y)*8+x)*64 + m] = D[m,c,y,x]
__global__ void prep_dt_kernel(const float* __restrict__ D,
                               float* __restrict__ DT) {
    int idx = blockIdx.x * 256 + threadIdx.x;
    if (idx < CIN*KS*KS*ATOMS) {
        int m = idx & 63;
        int r = idx >> 6;
        int xk = r & 7, y = (r >> 3) & 7, c = r >> 6;
        DT[idx] = D[((m*CIN + c)*KS + y)*KS + xk];
    }
}

// 9 table-sets (inclusion-exclusion for boundary classes), 9 dpq each.
// tbl: 0=T0(all) 1=-dY1 2=-dY2 3=-dX1 4=-dX2 5=+dC11 6=+dC12 7=+dC21 8=+dC22
__global__ void prep_gram_kernel(const float* __restrict__ DT,
                                 float* __restrict__ G) {
    int blk = blockIdx.x;              // td*16 + nchunk
    int td = blk >> 4;
    int tbl = td / 9, dpq = td % 9;
    int dp = dpq / 3, dq = dpq % 3;
    int di = 1 - dp, dj = 1 - dq;
    int ylo = (0 > -4*di) ? 0 : -4*di;
    int yhi = (8 < 8-4*di) ? 8 : 8-4*di;
    int xlo = (0 > -4*dj) ? 0 : -4*dj;
    int xhi = (8 < 8-4*dj) ? 8 : 8-4*dj;
    if (tbl==1 || tbl==5 || tbl==6) { if (yhi > 2) yhi = 2; }
    if (tbl==2 || tbl==7 || tbl==8) { if (ylo < 6) ylo = 6; }
    if (tbl==3 || tbl==5 || tbl==7) { if (xhi > 2) xhi = 2; }
    if (tbl==4 || tbl==6 || tbl==8) { if (xlo < 6) xlo = 6; }
    float sign = (tbl >= 1 && tbl <= 4) ? -1.f : 1.f;
    int t = threadIdx.x;
    int m = t & 63;
    int n = (blk & 15)*4 + (t >> 6);
    float s = 0.f;
    for (int c = 0; c < CIN; ++c)
        for (int y = ylo; y < yhi; ++y)
            for (int x = xlo; x < xhi; ++x)
                s += DT[((c*8+y)*8+x)*64 + m] *
                     DT[((c*8+y+4*di)*8 + (x+4*dj))*64 + n];
    G[td*4096 + n*64 + m] = sign * s;
}

// Pack G into MFMA A-operand layout, split FP16 hi/lo.
__global__ void prep_packg_kernel(const float* __restrict__ G,
                                  unsigned short* __restrict__ GAh,
                                  unsigned short* __restrict__ GAl) {
    int g = blockIdx.x * 256 + threadIdx.x;      // 162*256 = 41472 groups
    int lane = g & 63;
    int r = g >> 6;
    int kstep = r & 3; r >>= 2;
    int mhalf = r & 1; int td = r >> 1;          // tbl*9+dpq
    int m = mhalf*32 + (lane & 31);
    int n = kstep*16 + (lane >> 5)*8;
    const float* src = G + td*4096 + n*64 + m;
#pragma unroll
    for (int j = 0; j < 8; ++j) {
        float v = src[j*64];
        unsigned short h = f2h(v);
        GAh[g*8 + j] = h;
        GAl[g*8 + j] = f2h(v - h2f(h));
    }
}

// Pack D into MFMA A-layout for conv_b: K=192, k = c*64+y*8+x. (bf16 split)
__global__ void prep_packd_kernel(const float* __restrict__ D,
                                  unsigned short* __restrict__ DAh,
                                  unsigned short* __restrict__ DAl) {
    int g = blockIdx.x * 256 + threadIdx.x;
    if (g >= 1536) return;
    int lane = g & 63;
    int r = g >> 6;
    int kstep = r % 12, mhalf = r / 12;
    int m = mhalf*32 + (lane & 31);
    int k0 = kstep*16 + (lane >> 5)*8;
#pragma unroll
    for (int j = 0; j < 8; ++j) {
        float v = D[m*192 + k0 + j];
        unsigned short h = f2bf(v);
        DAh[g*8 + j] = h;
        DAl[g*8 + j] = f2bf(v - bf2f(h));
    }
}

// b = conv2d(x, D, stride4, pad2); u = 0.1*b. Output CHANNEL-LAST [i][j][n].
__global__ __launch_bounds__(256) void conv_b_kernel(
        const float* __restrict__ x,
        const unsigned short* __restrict__ DAh,
        const unsigned short* __restrict__ DAl,
        float* __restrict__ b, float* __restrict__ u) {
    __shared__ __align__(16) unsigned short xth[CIN*36*36];
    __shared__ __align__(16) unsigned short xtl[CIN*36*36];
    __shared__ float ot[64*65];
    int blk = blockIdx.x;
    int img = blk / 49, tile = blk % 49;
    int i0 = (tile / 7) * 8, j0 = (tile % 7) * 8;
    int t = threadIdx.x;
    int r0 = 4*i0 - 2, c0 = 4*j0 - 2;
    for (int f = t; f < CIN*36*36; f += 256) {
        int cc = f / 1296, rem = f % 1296;
        int rr = rem / 36, qq = rem % 36;
        int Y = r0 + rr, X = c0 + qq;
        float v = 0.f;
        if (Y >= 0 && Y < H && X >= 0 && X < W)
            v = x[((img*CIN + cc)*H + Y)*W + X];
        unsigned short h = f2bf(v);
        xth[f] = h;
        xtl[f] = f2bf(v - bf2f(h));
    }
    __syncthreads();
    int lane = t & 63, wave = t >> 6;
    int mhalf = wave & 1, poshalf = wave >> 1;
    int pos = poshalf*32 + (lane & 31), pi = pos >> 3, pj = pos & 7;
    int khalf = lane >> 5;
    floatx16 acc;
#pragma unroll
    for (int i = 0; i < 16; ++i) acc[i] = 0.f;
    const uint4* Ah4 = (const uint4*)DAh;
    const uint4* Al4 = (const uint4*)DAl;
#pragma unroll 3
    for (int kstep = 0; kstep < 12; ++kstep) {
        int k0 = kstep*16 + khalf*8;
        int cc = k0 >> 6, yy = (k0 >> 3) & 7;
        int boff = cc*1296 + (4*pi + yy)*36 + 4*pj;
        FragU ah, al, bh, bl;
        ah.u = Ah4[(mhalf*12 + kstep)*64 + lane];
        al.u = Al4[(mhalf*12 + kstep)*64 + lane];
        const uint2* ph = (const uint2*)(xth + boff);
        uint2 h0 = ph[0], h1 = ph[1];
        bh.u = make_uint4(h0.x, h0.y, h1.x, h1.y);
        const uint2* pl = (const uint2*)(xtl + boff);
        uint2 l0 = pl[0], l1 = pl[1];
        bl.u = make_uint4(l0.x, l0.y, l1.x, l1.y);
        acc = __builtin_amdgcn_mfma_f32_32x32x16_bf16(ah.v, bh.v, acc, 0, 0, 0);
        acc = __builtin_amdgcn_mfma_f32_32x32x16_bf16(ah.v, bl.v, acc, 0, 0, 0);
        acc = __builtin_amdgcn_mfma_f32_32x32x16_bf16(al.v, bh.v, acc, 0, 0, 0);
    }
#pragma unroll
    for (int r16 = 0; r16 < 16; ++r16) {
        int row = (r16 & 3) + 8*(r16 >> 2) + 4*khalf;
        ot[(mhalf*32 + row)*65 + pos] = acc[r16];
    }
    __syncthreads();
    int m = t & 63;
    float* bp = b + (size_t)img*IMGSZ;
    float* up = u + (size_t)img*IMGSZ;
#pragma unroll
    for (int e = 0; e < 16; ++e) {
        int pp = e*4 + (t >> 6);
        int gi = i0 + (pp >> 3), gj = j0 + (pp & 7);
        int gidx = (gi*OW + gj)*64 + m;
        float v = ot[m*65 + pp];
        bp[gidx] = v;
        up[gidx] = ETA * v;
    }
}

// ---- MFMA helpers ----
__device__ __forceinline__ void load_a(uint4 (&A)[9], const uint4* __restrict__ Gh4,
                                       const uint4* __restrict__ Gl4,
                                       int txoff, int bb, int mhalf, int lane) {
    int dq = bb >> 2, ks = bb & 3;
#pragma unroll
    for (int dp = 0; dp < 3; ++dp) {
        int abase = (((3*dp + dq)*2 + mhalf)*4 + ks)*64 + lane;
        A[dp*3+0] = Gh4[abase];
        A[dp*3+1] = Gl4[abase];
        A[dp*3+2] = Gh4[txoff + abase];
    }
}
__device__ __forceinline__ void load_b4(uint4 (&B)[4], const uint4* __restrict__ B4h,
                                        int bb, int khalf, int pjx) {
    int dq = bb >> 2, ks = bb & 3;
    int kg2 = ks*2 + khalf;
#pragma unroll
    for (int p = 0; p < 4; ++p) {
        int rc = p*58 + pjx + dq;
        B[p] = B4h[rc*8 + (kg2 ^ (rc & 7))];
    }
}
__device__ __forceinline__ void load_b8(uint4 (&B)[8], const uint4* __restrict__ B4h,
                                        int bb, int khalf, int pjx) {
    int dq = bb >> 2, ks = bb & 3;
    int kg2 = ks*2 + khalf;
#pragma unroll
    for (int p = 0; p < 4; ++p) {
        int rc0 = p*58 + pjx + dq;
        int rc1 = rc0 + 116;
        B[p]   = B4h[rc0*8 + (kg2 ^ (rc0 & 7))];
        B[4+p] = B4h[rc1*8 + (kg2 ^ (rc1 & 7))];
    }
}
__device__ __forceinline__ void do_mfma(floatx16& acc0, floatx16& acc1,
                                        const uint4 (&A)[9], const uint4 (&B)[4],
                                        unsigned msel) {
    __builtin_amdgcn_s_setprio(1);
#pragma unroll
    for (int dp = 0; dp < 3; ++dp) {
        FragH a0, a1, ax, b0, b1, bm0, bm1;
        a0.u = A[dp*3+0]; a1.u = A[dp*3+1]; ax.u = A[dp*3+2];
        b0.u = B[dp]; b1.u = B[dp+1];
        bm0.u = make_uint4(b0.u.x & msel, b0.u.y & msel,
                           b0.u.z & msel, b0.u.w & msel);
        bm1.u = make_uint4(b1.u.x & msel, b1.u.y & msel,
                           b1.u.z & msel, b1.u.w & msel);
        acc0 = __builtin_amdgcn_mfma_f32_32x32x16_f16(a0.v, b0.v, acc0, 0,0,0);
        acc1 = __builtin_amdgcn_mfma_f32_32x32x16_f16(a0.v, b1.v, acc1, 0,0,0);
        acc0 = __builtin_amdgcn_mfma_f32_32x32x16_f16(a1.v, b0.v, acc0, 0,0,0);
        acc1 = __builtin_amdgcn_mfma_f32_32x32x16_f16(a1.v, b1.v, acc1, 0,0,0);
        acc0 = __builtin_amdgcn_mfma_f32_32x32x16_f16(ax.v, bm0.v, acc0, 0,0,0);
        acc1 = __builtin_amdgcn_mfma_f32_32x32x16_f16(ax.v, bm1.v, acc1, 0,0,0);
    }
    __builtin_amdgcn_s_setprio(0);
}
// two row-pairs sharing the same A fragments (halves Gram-table traffic)
__device__ __forceinline__ void do_mfma2(floatx16& a00, floatx16& a01,
                                         floatx16& a10, floatx16& a11,
                                         const uint4 (&A)[9], const uint4 (&B)[8],
                                         unsigned msel) {
    __builtin_amdgcn_s_setprio(1);
#pragma unroll
    for (int dp = 0; dp < 3; ++dp) {
        FragH a0, a1, ax;
        a0.u = A[dp*3+0]; a1.u = A[dp*3+1]; ax.u = A[dp*3+2];
        FragH b0, b1, bm0, bm1;
        b0.u = B[dp]; b1.u = B[dp+1];
        bm0.u = make_uint4(b0.u.x & msel, b0.u.y & msel,
                           b0.u.z & msel, b0.u.w & msel);
        bm1.u = make_uint4(b1.u.x & msel, b1.u.y & msel,
                           b1.u.z & msel, b1.u.w & msel);
        a00 = __builtin_amdgcn_mfma_f32_32x32x16_f16(a0.v, b0.v, a00, 0,0,0);
        a01 = __builtin_amdgcn_mfma_f32_32x32x16_f16(a0.v, b1.v, a01, 0,0,0);
        a00 = __builtin_amdgcn_mfma_f32_32x32x16_f16(a1.v, b0.v, a00, 0,0,0);
        a01 = __builtin_amdgcn_mfma_f32_32x32x16_f16(a1.v, b1.v, a01, 0,0,0);
        a00 = __builtin_amdgcn_mfma_f32_32x32x16_f16(ax.v, bm0.v, a00, 0,0,0);
        a01 = __builtin_amdgcn_mfma_f32_32x32x16_f16(ax.v, bm1.v, a01, 0,0,0);
        FragH c0, c1, cm0, cm1;
        c0.u = B[4+dp]; c1.u = B[4+dp+1];
        cm0.u = make_uint4(c0.u.x & msel, c0.u.y & msel,
                           c0.u.z & msel, c0.u.w & msel);
        cm1.u = make_uint4(c1.u.x & msel, c1.u.y & msel,
                           c1.u.z & msel, c1.u.w & msel);
        a10 = __builtin_amdgcn_mfma_f32_32x32x16_f16(a0.v, c0.v, a10, 0,0,0);
        a11 = __builtin_amdgcn_mfma_f32_32x32x16_f16(a0.v, c1.v, a11, 0,0,0);
        a10 = __builtin_amdgcn_mfma_f32_32x32x16_f16(a1.v, c0.v, a10, 0,0,0);
        a11 = __builtin_amdgcn_mfma_f32_32x32x16_f16(a1.v, c1.v, a11, 0,0,0);
        a10 = __builtin_amdgcn_mfma_f32_32x32x16_f16(ax.v, cm0.v, a10, 0,0,0);
        a11 = __builtin_amdgcn_mfma_f32_32x32x16_f16(ax.v, cm1.v, a11, 0,0,0);
    }
    __builtin_amdgcn_s_setprio(0);
}
// term-loop pair with boundary-correction params; ym=0 -> interior terms only
__device__ __forceinline__ void edge_pair(floatx16& a0r, floatx16& a1r,
        const uint4* __restrict__ B4h, const uint4* __restrict__ Gh4,
        const uint4* __restrict__ Gl4, int slot0, int pjx,
        int mhalf, int khalf, int lane, int tbx, unsigned msel,
        int ym, int tby, int tbc) {
#pragma unroll 1
    for (int dq = 0; dq < 3; ++dq) {
#pragma unroll 1
        for (int kstep = 0; kstep < 4; ++kstep) {
            int kg2 = kstep*2 + khalf;
#pragma unroll
            for (int dp = 0; dp < 3; ++dp) {
                int rc0 = (slot0 + dp)*58 + pjx + dq;
                int rc1 = rc0 + 58;
                FragH B0, B1;
                B0.u = B4h[rc0*8 + (kg2 ^ (rc0 & 7))];
                B1.u = B4h[rc1*8 + (kg2 ^ (rc1 & 7))];
                for (int tm = 0; tm < 6; ++tm) {
                    int td = (tm < 2) ? 0 : (tm == 2) ? tbx : (tm < 5) ? tby : tbc;
                    const uint4* Ap = ((tm == 1) || (tm == 4)) ? Gl4 : Gh4;
                    bool masked = (tm == 2) || (tm == 5);
                    int am = (tm < 3) ? 3 : ym;
                    FragH a;
                    a.u = Ap[(((td*9 + 3*dp + dq)*2 + mhalf)*4 + kstep)*64 + lane];
                    if (!masked) {
                        if (am & 1)
                            a0r = __builtin_amdgcn_mfma_f32_32x32x16_f16(a.v, B0.v, a0r, 0,0,0);
                        if (am & 2)
                            a1r = __builtin_amdgcn_mfma_f32_32x32x16_f16(a.v, B1.v, a1r, 0,0,0);
                    } else {
                        if (am & 1) {
                            FragH bm;
                            bm.u = make_uint4(B0.u.x & msel, B0.u.y & msel,
                                              B0.u.z & msel, B0.u.w & msel);
                            a0r = __builtin_amdgcn_mfma_f32_32x32x16_f16(a.v, bm.v, a0r, 0,0,0);
                        }
                        if (am & 2) {
                            FragH bm;
                            bm.u = make_uint4(B1.u.x & msel, B1.u.y & msel,
                                              B1.u.z & msel, B1.u.w & msel);
                            a1r = __builtin_amdgcn_mfma_f32_32x32x16_f16(a.v, bm.v, a1r, 0,0,0);
                        }
                    }
                }
            }
        }
    }
}

// ---- epilogue helpers (transpose-free: direct from accs) ----
// u_{k+1} for one row: update u from acc, write a_{k+1} fp16 swizzled into
// stage2, save un into sv (caller passes dummy for discarded rows).
__device__ __forceinline__ void epi1_row(const floatx16& A, int ir, int pr,
        int pj, int mbase, const float* __restrict__ ub,
        const float* __restrict__ bp, unsigned short* __restrict__ st2,
        float (&sv)[16]) {
    if (pj >= 56 || ir < 0 || ir > 55) return;
    int C = pj + 1;
    int key2 = (2*pr + C) & 7;
    unsigned short* cell = st2 + (pr*58 + C)*64;
#pragma unroll
    for (int q = 0; q < 4; ++q) {
        int n0 = mbase + 8*q;
        const float4 uv = *(const float4*)(ub + (ir*OW + pj)*64 + n0);
        const float4 bv = *(const float4*)(bp + (ir*OW + pj)*64 + n0);
        float u0 = uv.x + ETA*(bv.x - uv.x - A[q*4+0] + softthr(uv.x));
        float u1 = uv.y + ETA*(bv.y - uv.y - A[q*4+1] + softthr(uv.y));
        float u2 = uv.z + ETA*(bv.z - uv.z - A[q*4+2] + softthr(uv.z));
        float u3 = uv.w + ETA*(bv.w - uv.w - A[q*4+3] + softthr(uv.w));
        ushort4 av = make_ushort4(f2h(softthr(u0)), f2h(softthr(u1)),
                                  f2h(softthr(u2)), f2h(softthr(u3)));
        *(ushort4*)(cell + (((n0 >> 3) ^ key2) << 3) + (n0 & 7)) = av;
        sv[q*4+0] = u0; sv[q*4+1] = u1; sv[q*4+2] = u2; sv[q*4+3] = u3;
    }
}
__device__ __forceinline__ void epi2_row(const floatx16& A2, const float (&sv)[16],
        int ir, int pj, int mbase, const float* __restrict__ bp,
        float* __restrict__ uo) {
    if (pj >= 56) return;
#pragma unroll
    for (int q = 0; q < 4; ++q) {
        int n0 = mbase + 8*q;
        const float4 bv = *(const float4*)(bp + (ir*OW + pj)*64 + n0);
        float4 w;
        w.x = sv[q*4+0] + ETA*(bv.x - sv[q*4+0] - A2[q*4+0] + softthr(sv[q*4+0]));
        w.y = sv[q*4+1] + ETA*(bv.y - sv[q*4+1] - A2[q*4+1] + softthr(sv[q*4+1]));
        w.z = sv[q*4+2] + ETA*(bv.z - sv[q*4+2] - A2[q*4+2] + softthr(sv[q*4+2]));
        w.w = sv[q*4+3] + ETA*(bv.w - sv[q*4+3] - A2[q*4+3] + softthr(sv[q*4+3]));
        *(float4*)(uo + (ir*OW + pj)*64 + n0) = w;
    }
}
__device__ __forceinline__ void fin_row(const floatx16& A2, int ir, int pj,
        int mbase, const float* __restrict__ ub, const float* __restrict__ bp,
        float* __restrict__ out, int img) {
    if (pj >= 56) return;
#pragma unroll
    for (int q = 0; q < 4; ++q) {
        int n0 = mbase + 8*q;
        const float4 uv = *(const float4*)(ub + (ir*OW + pj)*64 + n0);
        const float4 bv = *(const float4*)(bp + (ir*OW + pj)*64 + n0);
        float u0 = uv.x + ETA*(bv.x - uv.x - A2[q*4+0] + softthr(uv.x));
        float u1 = uv.y + ETA*(bv.y - uv.y - A2[q*4+1] + softthr(uv.y));
        float u2 = uv.z + ETA*(bv.z - uv.z - A2[q*4+2] + softthr(uv.z));
        float u3 = uv.w + ETA*(bv.w - uv.w - A2[q*4+3] + softthr(uv.w));
        size_t base = (((size_t)img*ATOMS + n0)*OH + ir)*OW + pj;
        out[base]            = softthr(u0);
        out[base + OH*OW]    = softthr(u1);
        out[base + 2*OH*OW]  = softthr(u2);
        out[base + 3*OH*OW]  = softthr(u3);
    }
}

// Two fused LCA iterations per launch on a 2-row band (transpose-free).
// Step 1 computes u_{k+1}/a_{k+1} on 4 rows (2 redundant border rows),
// a_{k+1} kept in LDS, own-row u_{k+1} kept in registers; step 2 computes
// u_{k+2} on the 2 own rows. u is ping-pong double-buffered (no race).
__global__ __launch_bounds__(256, 2) void lca_fused_kernel(
        const float* __restrict__ b, const float* __restrict__ uin,
        float* __restrict__ uout,
        const unsigned short* __restrict__ GAh,
        const unsigned short* __restrict__ GAl) {
    __shared__ __align__(16) unsigned char smem[74240];  // 44544 + 29696
    unsigned short* st1 = (unsigned short*)smem;          // 6 rows a_k
    unsigned short* st2 = (unsigned short*)(smem + 44544);// 4 rows a_{k+1}
    int blk = blockIdx.x;
    int img = blk / 28, bandi = blk % 28;
    int i0 = bandi*2;
    int t = threadIdx.x;
    const float* ub = uin + (size_t)img*IMGSZ;
    const float* bp = b + (size_t)img*IMGSZ;
    float* uo = uout + (size_t)img*IMGSZ;
    bool edge = (bandi == 0) || (bandi == 27);
    // Phase A0: zero stage-2 halo cols (C=0,57); edge: zero halo row slot.
    if (t < 128) {
        int cell = t >> 4, q = t & 15;
        int srow = cell >> 1, side = cell & 1;
        *(ushort4*)(st2 + (srow*58 + side*57)*64 + q*4) = make_ushort4(0,0,0,0);
    }
    if (edge) {
        int zslot = (bandi == 0) ? 0 : 3;
        for (int idx = t; idx < 56*16; idx += 256) {
            int C = 1 + (idx >> 4), q = idx & 15;
            *(ushort4*)(st2 + (zslot*58 + C)*64 + q*4) = make_ushort4(0,0,0,0);
        }
    }
    // Phase A1: stage1 = softthr(u_k), rows i0-2..i0+3 (6 slots), swizzled.
    for (int idx = t; idx < 6*58*16; idx += 256) {
        int n0 = (idx & 15) * 4;
        int cc = idx >> 4;
        int srow = cc / 58, C = cc - 58*srow;
        int r = i0 - 2 + srow, c = C - 1;
        float4 v = make_float4(0.f, 0.f, 0.f, 0.f);
        if (r >= 0 && r < OH && c >= 0 && c < OW)
            v = *(const float4*)(ub + (r*OW + c)*64 + n0);
        ushort4 h = make_ushort4(f2h(softthr(v.x)), f2h(softthr(v.y)),
                                 f2h(softthr(v.z)), f2h(softthr(v.w)));
        int key = (2*srow + C) & 7;
        *(ushort4*)(st1 + cc*64 + (((n0 >> 3) ^ key) << 3) + (n0 & 7)) = h;
    }
    __syncthreads();
    int lane = t & 63, wave = t >> 6;
    int mhalf = wave & 1, cgrp = wave >> 1;
    int khalf = lane >> 5, cl = lane & 31;
    int pj = cgrp*32 + cl;
    int pjx = (pj < 56) ? pj : 0;
    int mbase = mhalf*32 + 4*khalf;
    const uint4* Gh4 = (const uint4*)GAh;
    const uint4* Gl4 = (const uint4*)GAl;
    const uint4* B1p = (const uint4*)st1;
    const uint4* B2p = (const uint4*)st2;
    int tbx = (cgrp == 0) ? 3 : 4;
    int txoff = tbx * 9 * 512;
    unsigned msel = (cl == ((cgrp == 0) ? 0 : 23)) ? 0xFFFFFFFFu : 0u;
    int tby = (bandi == 0) ? 1 : 2;
    int tbc = (bandi == 0) ? ((cgrp == 0) ? 5 : 6) : ((cgrp == 0) ? 7 : 8);
    floatx16 a00, a01, a10, a11;
#pragma unroll
    for (int i = 0; i < 16; ++i) { a00[i]=0.f; a01[i]=0.f; a10[i]=0.f; a11[i]=0.f; }
    if (!edge) {
        uint4 Aa[9], Ab[9], Ba[8], Bb[8];
        load_a(Aa, Gh4, Gl4, txoff, 0, mhalf, lane);
        load_b8(Ba, B1p, 0, khalf, pjx);
#pragma unroll 1
        for (int it2 = 0; it2 < 6; ++it2) {
            int bb = it2*2;
            load_a(Ab, Gh4, Gl4, txoff, bb+1, mhalf, lane);
            load_b8(Bb, B1p, bb+1, khalf, pjx);
            do_mfma2(a00, a01, a10, a11, Aa, Ba, msel);
            if (it2 < 5) {
                load_a(Aa, Gh4, Gl4, txoff, bb+2, mhalf, lane);
                load_b8(Ba, B1p, bb+2, khalf, pjx);
            }
            do_mfma2(a00, a01, a10, a11, Ab, Bb, msel);
        }
    } else {
        int ym0 = (bandi == 0) ? 2 : 0;    // pair0 rows (i0-1,i0)
        int ym1 = (bandi == 0) ? 0 : 1;    // pair1 rows (i0+1,i0+2)
        edge_pair(a00, a01, B1p, Gh4, Gl4, 0, pjx, mhalf, khalf, lane,
                  tbx, msel, ym0, tby, tbc);
        edge_pair(a10, a11, B1p, Gh4, Gl4, 2, pjx, mhalf, khalf, lane,
                  tbx, msel, ym1, tby, tbc);
    }
    // Epilogue 1: u_{k+1} on 4 rows; a_{k+1} -> stage2; keep own-row u.
    float ur2a[16], ur2b[16], dum[16];
    epi1_row(a00, i0-1, 0, pj, mbase, ub, bp, st2, dum);
    epi1_row(a01, i0,   1, pj, mbase, ub, bp, st2, ur2a);
    epi1_row(a10, i0+1, 2, pj, mbase, ub, bp, st2, ur2b);
    epi1_row(a11, i0+2, 3, pj, mbase, ub, bp, st2, dum);
    __syncthreads();
    // Step 2: Gram on pair (i0, i0+1) from stage2 (slots 0..3).
    floatx16 c0, c1;
#pragma unroll
    for (int i = 0; i < 16; ++i) { c0[i] = 0.f; c1[i] = 0.f; }
    if (!edge) {
        uint4 Aa[9], Ab[9], Ba[4], Bb[4];
        load_a(Aa, Gh4, Gl4, txoff, 0, mhalf, lane);
        load_b4(Ba, B2p, 0, khalf, pjx);
#pragma unroll 1
        for (int it2 = 0; it2 < 6; ++it2) {
            int bb = it2*2;
            load_a(Ab, Gh4, Gl4, txoff, bb+1, mhalf, lane);
            load_b4(Bb, B2p, bb+1, khalf, pjx);
            do_mfma(c0, c1, Aa, Ba, msel);
            if (it2 < 5) {
                load_a(Aa, Gh4, Gl4, txoff, bb+2, mhalf, lane);
                load_b4(Ba, B2p, bb+2, khalf, pjx);
            }
            do_mfma(c0, c1, Ab, Bb, msel);
        }
    } else {
        int ym2 = (bandi == 0) ? 1 : 2;
        edge_pair(c0, c1, B2p, Gh4, Gl4, 0, pjx, mhalf, khalf, lane,
                  tbx, msel, ym2, tby, tbc);
    }
    // Epilogue 2: u_{k+2} on own rows -> uout.
    epi2_row(c0, ur2a, i0,   pj, mbase, bp, uo);
    epi2_row(c1, ur2b, i0+1, pj, mbase, bp, uo);
}

// Final single iteration (iter 10): stage a=soft(u) from u, one Gram step,
// write softthr(u_new) to out.
__global__ __launch_bounds__(256, 2) void lca_final_kernel(
        const float* __restrict__ b, const float* __restrict__ uin,
        const unsigned short* __restrict__ GAh,
        const unsigned short* __restrict__ GAl,
        float* __restrict__ out) {
    __shared__ __align__(16) unsigned char smem[29696];
    unsigned short* st1 = (unsigned short*)smem;
    int blk = blockIdx.x;
    int img = blk / 28, bandi = blk % 28;
    int i0 = bandi*2;
    int t = threadIdx.x;
    const float* ub = uin + (size_t)img*IMGSZ;
    const float* bp = b + (size_t)img*IMGSZ;
    bool edge = (bandi == 0) || (bandi == 27);
    // stage rows i0-1..i0+2 (4 slots)
    for (int idx = t; idx < 4*58*16; idx += 256) {
        int n0 = (idx & 15) * 4;
        int cc = idx >> 4;
        int srow = cc / 58, C = cc - 58*srow;
        int r = i0 - 1 + srow, c = C - 1;
        float4 v = make_float4(0.f, 0.f, 0.f, 0.f);
        if (r >= 0 && r < OH && c >= 0 && c < OW)
            v = *(const float4*)(ub + (r*OW + c)*64 + n0);
        ushort4 h = make_ushort4(f2h(softthr(v.x)), f2h(softthr(v.y)),
                                 f2h(softthr(v.z)), f2h(softthr(v.w)));
        int key = (2*srow + C) & 7;
        *(ushort4*)(st1 + cc*64 + (((n0 >> 3) ^ key) << 3) + (n0 & 7)) = h;
    }
    __syncthreads();
    int lane = t & 63, wave = t >> 6;
    int mhalf = wave & 1, cgrp = wave >> 1;
    int khalf = lane >> 5, cl = lane & 31;
    int pj = cgrp*32 + cl;
    int pjx = (pj < 56) ? pj : 0;
    int mbase = mhalf*32 + 4*khalf;
    const uint4* Gh4 = (const uint4*)GAh;
    const uint4* Gl4 = (const uint4*)GAl;
    const uint4* B1p = (const uint4*)st1;
    int tbx = (cgrp == 0) ? 3 : 4;
    int txoff = tbx * 9 * 512;
    unsigned msel = (cl == ((cgrp == 0) ? 0 : 23)) ? 0xFFFFFFFFu : 0u;
    floatx16 c0, c1;
#pragma unroll
    for (int i = 0; i < 16; ++i) { c0[i] = 0.f; c1[i] = 0.f; }
    if (!edge) {
        uint4 Aa[9], Ab[9], Ba[4], Bb[4];
        load_a(Aa, Gh4, Gl4, txoff, 0, mhalf, lane);
        load_b4(Ba, B1p, 0, khalf, pjx);
#pragma unroll 1
        for (int it2 = 0; it2 < 6; ++it2) {
            int bb = it2*2;
            load_a(Ab, Gh4, Gl4, txoff, bb+1, mhalf, lane);
            load_b4(Bb, B1p, bb+1, khalf, pjx);
            do_mfma(c0, c1, Aa, Ba, msel);
            if (it2 < 5) {
                load_a(Aa, Gh4, Gl4, txoff, bb+2, mhalf, lane);
                load_b4(Ba, B1p, bb+2, khalf, pjx);
            }
            do_mfma(c0, c1, Ab, Bb, msel);
        }
    } else {
        int tby = (bandi == 0) ? 1 : 2;
        int tbc = (bandi == 0) ? ((cgrp == 0) ? 5 : 6) : ((cgrp == 0) ? 7 : 8);
        int ym = (bandi == 0) ? 1 : 2;
        edge_pair(c0, c1, B1p, Gh4, Gl4, 0, pjx, mhalf, khalf, lane,
                  tbx, msel, ym, tby, tbc);
    }
    fin_row(c0, i0,   pj, mbase, ub, bp, out, img);
    fin_row(c1, i0+1, pj, mbase, ub, bp, out, img);
}

extern "C" void kernel_launch(void* const* d_in, const int* in_sizes, int n_in,
                              void* d_out, int out_size, void* d_ws, size_t ws_size,
                              hipStream_t stream) {
    const float* x = (const float*)d_in[0];
    const float* D = (const float*)d_in[1];
    float* out = (float*)d_out;
    float* ws = (float*)d_ws;
    float* b  = ws;                        // NLAT f32 (channel-last)
    float* u0 = b  + NLAT;                 // NLAT f32 (ping)
    float* u1 = u0 + NLAT;                 // NLAT f32 (pong)
    float* DT = u1 + NLAT;                 // 12288 f32
    float* Gf = DT + 12288;                // 81*4096 f32
    unsigned short* GAh = (unsigned short*)(Gf + 331776);
    unsigned short* GAl = GAh + 331776;
    unsigned short* DAh = GAl + 331776;
    unsigned short* DAl = DAh + 12288;
    prep_dt_kernel<<<48, 256, 0, stream>>>(D, DT);
    prep_gram_kernel<<<1296, 256, 0, stream>>>(DT, Gf);
    prep_packg_kernel<<<162, 256, 0, stream>>>(Gf, GAh, GAl);
    prep_packd_kernel<<<6, 256, 0, stream>>>(D, DAh, DAl);
    conv_b_kernel<<<BATCH*49, 256, 0, stream>>>(x, DAh, DAl, b, u0);   // iter 1
    // iters 2..9 as four fused double-steps (u ping-pong)
    lca_fused_kernel<<<BATCH*28, 256, 0, stream>>>(b, u0, u1, GAh, GAl);
    lca_fused_kernel<<<BATCH*28, 256, 0, stream>>>(b, u1, u0, GAh, GAl);
    lca_fused_kernel<<<BATCH*28, 256, 0, stream>>>(b, u0, u1, GAh, GAl);
    lca_fused_kernel<<<BATCH*28, 256, 0, stream>>>(b, u1, u0, GAh, GAl);
    // iter 10 -> out
    lca_final_kernel<<<BATCH*28, 256, 0, stream>>>(b, u0, GAh, GAl, out);
}